// Round 1
// baseline (126.573 us; speedup 1.0000x reference)
//
#include <hip/hip_runtime.h>
#include <cstdint>
#include <cstddef>

// Problem constants (from reference)
constexpr int B = 8, C = 96, N = 3136, K = 18;
constexpr float C1c = 1e-6f, C2c = 1e-6f;

// ---------------------------------------------------------------------------
// Kernel A: tiled transpose of x and x_p: [B,C,N] -> [B,N,C]
// ---------------------------------------------------------------------------
__global__ __launch_bounds__(256) void transpose2_kernel(
    const float* __restrict__ x, const float* __restrict__ xp,
    float* __restrict__ xT, float* __restrict__ xpT) {
  __shared__ float t0[32][33];
  __shared__ float t1[32][33];
  const int b = blockIdx.z;
  const int c0 = blockIdx.y * 32;
  const int n0 = blockIdx.x * 32;
  const int tx = threadIdx.x, ty = threadIdx.y;  // block (32, 8)
  const float* xb = x + (size_t)b * C * N;
  const float* xpb = xp + (size_t)b * C * N;
#pragma unroll
  for (int i = 0; i < 4; ++i) {
    const int c = c0 + ty + i * 8;
    t0[ty + i * 8][tx] = xb[(size_t)c * N + n0 + tx];
    t1[ty + i * 8][tx] = xpb[(size_t)c * N + n0 + tx];
  }
  __syncthreads();
  float* xTb = xT + (size_t)b * N * C;
  float* xpTb = xpT + (size_t)b * N * C;
#pragma unroll
  for (int i = 0; i < 4; ++i) {
    const int n = n0 + ty + i * 8;
    xTb[(size_t)n * C + c0 + tx] = t0[tx][ty + i * 8];
    xpTb[(size_t)n * C + c0 + tx] = t1[tx][ty + i * 8];
  }
}

// ---------------------------------------------------------------------------
// Kernel B: per-column mean / variance of x over the channel dim.
// colmean[b*N+m] = mean_c x[b,c,m]; colvar = E[x^2]-mean^2
// Reads original layout coalesced (consecutive threads = consecutive m).
// ---------------------------------------------------------------------------
__global__ __launch_bounds__(256) void colstats_kernel(
    const float* __restrict__ x, float* __restrict__ cmean,
    float* __restrict__ cvar) {
  const int idx = blockIdx.x * 256 + threadIdx.x;  // b*N + m
  if (idx >= B * N) return;
  const int b = idx / N;
  const int m = idx - b * N;
  const float* p = x + (size_t)b * C * N + m;
  float s = 0.f, s2 = 0.f;
#pragma unroll 4
  for (int c = 0; c < C; ++c) {
    const float v = p[(size_t)c * N];
    s += v;
    s2 += v * v;
  }
  const float mean = s * (1.0f / C);
  cmean[idx] = mean;
  cvar[idx] = s2 * (1.0f / C) - mean * mean;
}

// ---------------------------------------------------------------------------
// Kernel C: main fused kernel. One wave (64 lanes) per (b,n).
// Lane l owns channel c=l (all lanes) and c=l+64 (lanes < 32).
// Per k: gather 2 x-columns (contiguous 384B each), wave-reduce the dot,
// combine with precomputed col stats -> sff_k (broadcast on all lanes),
// then immediately accumulate the xp output term. Writes outT[B,N,C].
// ---------------------------------------------------------------------------
__global__ __launch_bounds__(256) void ssim_main_kernel(
    const float* __restrict__ xT, const float* __restrict__ xpT,
    const float* __restrict__ cmean, const float* __restrict__ cvar,
    const int* __restrict__ eidx, float* __restrict__ outT) {
  __shared__ int sh_idx[4][40];  // [wave][0..17: j, 18..35: i]
  const int wave = threadIdx.x >> 6;
  const int lane = threadIdx.x & 63;
  const int gn = blockIdx.x * 4 + wave;  // = b*N + n  (grid exact)
  const int b = gn / N;
  const int n = gn - b * N;

  if (lane < 36) {
    const int s = (lane >= 18) ? 1 : 0;  // 0 -> edge_index[0] (j), 1 -> [1] (i)
    const int k = lane - 18 * s;
    sh_idx[wave][lane] = eidx[((size_t)(s * B + b) * N + n) * K + k];
  }
  __syncthreads();

  const float* xb = xT + (size_t)b * N * C;
  const float* xpb = xpT + (size_t)b * N * C;
  const float* cm = cmean + (size_t)b * N;
  const float* cv = cvar + (size_t)b * N;

  const int c1 = lane;
  const int c2 = lane + 64;
  const bool has2 = (lane < 32);

  float acc1 = 0.f, acc2 = 0.f;
  for (int k = 0; k < K; ++k) {
    const int j = sh_idx[wave][k];
    const int i = sh_idx[wave][18 + k];
    const float* ci = xb + (size_t)i * C;
    const float* cj = xb + (size_t)j * C;
    float p = ci[c1] * cj[c1];
    if (has2) p += ci[c2] * cj[c2];
#pragma unroll
    for (int off = 32; off > 0; off >>= 1) p += __shfl_xor(p, off, 64);
    const float mi = cm[i], mj = cm[j];
    const float vi = cv[i], vj = cv[j];
    const float cov = p * (1.0f / C) - mi * mj;
    const float S1 = (2.f * mi * mj + C1c) / (mi * mi + mj * mj + C1c);
    const float S2 = (2.f * cov + C2c) / (vi + vj + C2c);
    const float sff = 1.f - S1 * S2;

    const float* pi = xpb + (size_t)i * C;
    const float* pj = xpb + (size_t)j * C;
    {
      const float a = pi[c1], q = pj[c1];
      acc1 += a + q + fabsf(a - q) * sff;
    }
    if (has2) {
      const float a = pi[c2], q = pj[c2];
      acc2 += a + q + fabsf(a - q) * sff;
    }
  }
  float* ob = outT + (size_t)gn * C;
  ob[c1] = acc1;
  if (has2) ob[c2] = acc2;
}

// ---------------------------------------------------------------------------
// Kernel D: transpose back outT [B,N,C] -> out [B,C,N]
// ---------------------------------------------------------------------------
__global__ __launch_bounds__(256) void transpose_back_kernel(
    const float* __restrict__ outT, float* __restrict__ out) {
  __shared__ float t[32][33];
  const int b = blockIdx.z;
  const int n0 = blockIdx.x * 32;
  const int c0 = blockIdx.y * 32;
  const int tx = threadIdx.x, ty = threadIdx.y;  // block (32, 8)
  const float* ib = outT + (size_t)b * N * C;
#pragma unroll
  for (int i = 0; i < 4; ++i) {
    const int n = n0 + ty + i * 8;
    t[ty + i * 8][tx] = ib[(size_t)n * C + c0 + tx];
  }
  __syncthreads();
  float* ob = out + (size_t)b * C * N;
#pragma unroll
  for (int i = 0; i < 4; ++i) {
    const int c = c0 + ty + i * 8;
    ob[(size_t)c * N + n0 + tx] = t[tx][ty + i * 8];
  }
}

// ---------------------------------------------------------------------------
// Fallback (only used if ws_size is too small): slow but correct,
// one thread per (b,n), reads strided original layout directly.
// ---------------------------------------------------------------------------
__global__ void fallback_kernel(const float* __restrict__ x,
                                const float* __restrict__ xp,
                                const int* __restrict__ e,
                                float* __restrict__ out) {
  const int gn = blockIdx.x * 64 + threadIdx.x;
  if (gn >= B * N) return;
  const int b = gn / N;
  const int n = gn - b * N;
  const float* xb = x + (size_t)b * C * N;
  const float* xpb = xp + (size_t)b * C * N;
  int ii[K], jj[K];
  float sff[K];
#pragma unroll
  for (int k = 0; k < K; ++k) {
    jj[k] = e[((size_t)(0 * B + b) * N + n) * K + k];
    ii[k] = e[((size_t)(1 * B + b) * N + n) * K + k];
    float si = 0, sj = 0, sii = 0, sjj = 0, sij = 0;
    for (int c = 0; c < C; ++c) {
      const float a = xb[(size_t)c * N + ii[k]];
      const float q = xb[(size_t)c * N + jj[k]];
      si += a; sj += q; sii += a * a; sjj += q * q; sij += a * q;
    }
    const float mi = si * (1.f / C), mj = sj * (1.f / C);
    const float vi = sii * (1.f / C) - mi * mi;
    const float vj = sjj * (1.f / C) - mj * mj;
    const float cov = sij * (1.f / C) - mi * mj;
    const float S1 = (2.f * mi * mj + C1c) / (mi * mi + mj * mj + C1c);
    const float S2 = (2.f * cov + C2c) / (vi + vj + C2c);
    sff[k] = 1.f - S1 * S2;
  }
  for (int c = 0; c < C; ++c) {
    float acc = 0.f;
#pragma unroll
    for (int k = 0; k < K; ++k) {
      const float a = xpb[(size_t)c * N + ii[k]];
      const float q = xpb[(size_t)c * N + jj[k]];
      acc += a + q + fabsf(a - q) * sff[k];
    }
    out[((size_t)b * C + c) * N + n] = acc;
  }
}

// ---------------------------------------------------------------------------
extern "C" void kernel_launch(void* const* d_in, const int* in_sizes, int n_in,
                              void* d_out, int out_size, void* d_ws, size_t ws_size,
                              hipStream_t stream) {
  const float* x = (const float*)d_in[0];
  const float* xp = (const float*)d_in[1];
  const int* e = (const int*)d_in[2];
  float* out = (float*)d_out;

  const size_t nBNC = (size_t)B * N * C;
  const size_t nBN = (size_t)B * N;
  const size_t need = (3 * nBNC + 2 * nBN) * sizeof(float);

  if (ws_size >= need) {
    float* ws = (float*)d_ws;
    float* xT = ws;
    float* xpT = xT + nBNC;
    float* cmean = xpT + nBNC;
    float* cvar = cmean + nBN;
    float* outT = cvar + nBN;

    transpose2_kernel<<<dim3(N / 32, C / 32, B), dim3(32, 8), 0, stream>>>(
        x, xp, xT, xpT);
    colstats_kernel<<<(B * N + 255) / 256, 256, 0, stream>>>(x, cmean, cvar);
    ssim_main_kernel<<<(B * N) / 4, 256, 0, stream>>>(xT, xpT, cmean, cvar, e,
                                                      outT);
    transpose_back_kernel<<<dim3(N / 32, C / 32, B), dim3(32, 8), 0, stream>>>(
        outT, out);
  } else {
    fallback_kernel<<<(B * N + 63) / 64, 64, 0, stream>>>(x, xp, e, out);
  }
}

// Round 2
// 75.410 us; speedup vs baseline: 1.6785x; 1.6785x over previous
//
#include <hip/hip_runtime.h>
#include <cstdint>
#include <cstddef>

// Problem constants (from reference)
constexpr int B = 8, C = 96, N = 3136, K = 18;
constexpr float C1c = 1e-6f, C2c = 1e-6f;

// ---------------------------------------------------------------------------
// Kernel A: tiled transpose of x and x_p: [B,C,N] -> [B,N,C]
// ---------------------------------------------------------------------------
__global__ __launch_bounds__(256) void transpose2_kernel(
    const float* __restrict__ x, const float* __restrict__ xp,
    float* __restrict__ xT, float* __restrict__ xpT) {
  __shared__ float t0[32][33];
  __shared__ float t1[32][33];
  const int b = blockIdx.z;
  const int c0 = blockIdx.y * 32;
  const int n0 = blockIdx.x * 32;
  const int tx = threadIdx.x, ty = threadIdx.y;  // block (32, 8)
  const float* xb = x + (size_t)b * C * N;
  const float* xpb = xp + (size_t)b * C * N;
#pragma unroll
  for (int i = 0; i < 4; ++i) {
    const int c = c0 + ty + i * 8;
    t0[ty + i * 8][tx] = xb[(size_t)c * N + n0 + tx];
    t1[ty + i * 8][tx] = xpb[(size_t)c * N + n0 + tx];
  }
  __syncthreads();
  float* xTb = xT + (size_t)b * N * C;
  float* xpTb = xpT + (size_t)b * N * C;
#pragma unroll
  for (int i = 0; i < 4; ++i) {
    const int n = n0 + ty + i * 8;
    xTb[(size_t)n * C + c0 + tx] = t0[tx][ty + i * 8];
    xpTb[(size_t)n * C + c0 + tx] = t1[tx][ty + i * 8];
  }
}

// ---------------------------------------------------------------------------
// Kernel B: per-column raw sums of x over channels: cstat[b*N+m] = {Σx, Σx²}
// (main kernel derives mean/var; keeps this kernel a pure coalesced stream)
// ---------------------------------------------------------------------------
__global__ __launch_bounds__(256) void colstats_kernel(
    const float* __restrict__ x, float2* __restrict__ cstat) {
  const int idx = blockIdx.x * 256 + threadIdx.x;  // b*N + m
  if (idx >= B * N) return;
  const int b = idx / N;
  const int m = idx - b * N;
  const float* p = x + (size_t)b * C * N + m;
  float s = 0.f, s2 = 0.f;
#pragma unroll 4
  for (int c = 0; c < C; ++c) {
    const float v = p[(size_t)c * N];
    s += v;
    s2 += v * v;
  }
  cstat[idx] = make_float2(s, s2);
}

// ---------------------------------------------------------------------------
// Kernel C: main fused kernel. One wave per (b,n); batch pinned to XCD via
// blockIdx & 7 (8 batches == 8 XCDs -> each XCD L2 holds one batch slice).
// Lane l owns channel c=l plus c=l+64 for l<32 (mask-multiplied, no branches).
// Phases: (1) 18 dot partials (all gathers independent, pipelined)
//         (2) 18 interleaved 6-step butterflies (independent shfl chains)
//         (3) per-k: sff from precomputed col sums, fused xp accumulation
// Indices are wave-uniform via readlane -> scalar addressing throughout.
// ---------------------------------------------------------------------------
__global__ __launch_bounds__(256) void ssim_main_kernel(
    const float* __restrict__ xT, const float* __restrict__ xpT,
    const float2* __restrict__ cstat, const int* __restrict__ eidx,
    float* __restrict__ outT) {
  const int wave = threadIdx.x >> 6;
  const int lane = threadIdx.x & 63;
  const int b = blockIdx.x & 7;          // XCD pin: batch == blockIdx % 8
  const int tile = blockIdx.x >> 3;
  const int n = tile * 4 + wave;

  // Per-lane index load: lanes 0..17 -> j_k (edge_index[0]),
  // lanes 18..35 -> i_k (edge_index[1]).
  int myidx = 0;
  if (lane < 36) {
    const int s = (lane >= 18) ? 1 : 0;
    const int k = lane - 18 * s;
    myidx = eidx[((size_t)(s * B + b) * N + n) * K + k];
  }

  const float* xb = xT + (size_t)b * N * C;
  const float* xpb = xpT + (size_t)b * N * C;
  const float2* cs = cstat + (size_t)b * N;

  const int c1 = lane;
  const int c2 = (lane < 32) ? lane + 64 : 95;  // clamped safe address
  const float m2 = (lane < 32) ? 1.f : 0.f;     // validity mask for c2

  int ji[K], jj[K];
  float p[K];
#pragma unroll
  for (int k = 0; k < K; ++k) {
    const int j = __builtin_amdgcn_readlane(myidx, k);
    const int i = __builtin_amdgcn_readlane(myidx, 18 + k);
    jj[k] = j;
    ji[k] = i;
    const float* ci = xb + (size_t)i * C;
    const float* cj = xb + (size_t)j * C;
    p[k] = ci[c1] * cj[c1] + m2 * (ci[c2] * cj[c2]);
  }

  // 18 independent butterflies, interleaved (offset outer, k inner)
#pragma unroll
  for (int off = 32; off > 0; off >>= 1) {
#pragma unroll
    for (int k = 0; k < K; ++k) p[k] += __shfl_xor(p[k], off, 64);
  }

  float acc1 = 0.f, acc2 = 0.f;
#pragma unroll
  for (int k = 0; k < K; ++k) {
    const float2 si = cs[ji[k]];
    const float2 sj = cs[jj[k]];
    const float mi = si.x * (1.0f / C), mj = sj.x * (1.0f / C);
    const float vi = si.y * (1.0f / C) - mi * mi;
    const float vj = sj.y * (1.0f / C) - mj * mj;
    const float cov = p[k] * (1.0f / C) - mi * mj;
    const float S1 =
        (2.f * mi * mj + C1c) * __builtin_amdgcn_rcpf(mi * mi + mj * mj + C1c);
    const float S2 = (2.f * cov + C2c) * __builtin_amdgcn_rcpf(vi + vj + C2c);
    const float sff = 1.f - S1 * S2;

    const float* pi = xpb + (size_t)ji[k] * C;
    const float* pj = xpb + (size_t)jj[k] * C;
    const float a1 = pi[c1], q1 = pj[c1];
    acc1 += a1 + q1 + fabsf(a1 - q1) * sff;
    const float a2 = pi[c2], q2 = pj[c2];
    acc2 += a2 + q2 + fabsf(a2 - q2) * sff;
  }

  float* ob = outT + ((size_t)b * N + n) * C;
  ob[c1] = acc1;
  if (lane < 32) ob[c2] = acc2;
}

// ---------------------------------------------------------------------------
// Kernel D: transpose back outT [B,N,C] -> out [B,C,N]
// ---------------------------------------------------------------------------
__global__ __launch_bounds__(256) void transpose_back_kernel(
    const float* __restrict__ outT, float* __restrict__ out) {
  __shared__ float t[32][33];
  const int b = blockIdx.z;
  const int n0 = blockIdx.x * 32;
  const int c0 = blockIdx.y * 32;
  const int tx = threadIdx.x, ty = threadIdx.y;  // block (32, 8)
  const float* ib = outT + (size_t)b * N * C;
#pragma unroll
  for (int i = 0; i < 4; ++i) {
    const int n = n0 + ty + i * 8;
    t[ty + i * 8][tx] = ib[(size_t)n * C + c0 + tx];
  }
  __syncthreads();
  float* ob = out + (size_t)b * C * N;
#pragma unroll
  for (int i = 0; i < 4; ++i) {
    const int c = c0 + ty + i * 8;
    ob[(size_t)c * N + n0 + tx] = t[tx][ty + i * 8];
  }
}

// ---------------------------------------------------------------------------
// Fallback (only used if ws_size is too small): slow but correct.
// ---------------------------------------------------------------------------
__global__ void fallback_kernel(const float* __restrict__ x,
                                const float* __restrict__ xp,
                                const int* __restrict__ e,
                                float* __restrict__ out) {
  const int gn = blockIdx.x * 64 + threadIdx.x;
  if (gn >= B * N) return;
  const int b = gn / N;
  const int n = gn - b * N;
  const float* xb = x + (size_t)b * C * N;
  const float* xpb = xp + (size_t)b * C * N;
  int ii[K], jj[K];
  float sff[K];
#pragma unroll
  for (int k = 0; k < K; ++k) {
    jj[k] = e[((size_t)(0 * B + b) * N + n) * K + k];
    ii[k] = e[((size_t)(1 * B + b) * N + n) * K + k];
    float si = 0, sj = 0, sii = 0, sjj = 0, sij = 0;
    for (int c = 0; c < C; ++c) {
      const float a = xb[(size_t)c * N + ii[k]];
      const float q = xb[(size_t)c * N + jj[k]];
      si += a; sj += q; sii += a * a; sjj += q * q; sij += a * q;
    }
    const float mi = si * (1.f / C), mj = sj * (1.f / C);
    const float vi = sii * (1.f / C) - mi * mi;
    const float vj = sjj * (1.f / C) - mj * mj;
    const float cov = sij * (1.f / C) - mi * mj;
    const float S1 = (2.f * mi * mj + C1c) / (mi * mi + mj * mj + C1c);
    const float S2 = (2.f * cov + C2c) / (vi + vj + C2c);
    sff[k] = 1.f - S1 * S2;
  }
  for (int c = 0; c < C; ++c) {
    float acc = 0.f;
#pragma unroll
    for (int k = 0; k < K; ++k) {
      const float a = xpb[(size_t)c * N + ii[k]];
      const float q = xpb[(size_t)c * N + jj[k]];
      acc += a + q + fabsf(a - q) * sff[k];
    }
    out[((size_t)b * C + c) * N + n] = acc;
  }
}

// ---------------------------------------------------------------------------
extern "C" void kernel_launch(void* const* d_in, const int* in_sizes, int n_in,
                              void* d_out, int out_size, void* d_ws, size_t ws_size,
                              hipStream_t stream) {
  const float* x = (const float*)d_in[0];
  const float* xp = (const float*)d_in[1];
  const int* e = (const int*)d_in[2];
  float* out = (float*)d_out;

  const size_t nBNC = (size_t)B * N * C;
  const size_t nBN = (size_t)B * N;
  const size_t need = 3 * nBNC * sizeof(float) + nBN * sizeof(float2);

  if (ws_size >= need) {
    float* ws = (float*)d_ws;
    float* xT = ws;
    float* xpT = xT + nBNC;
    float* outT = xpT + nBNC;
    float2* cstat = (float2*)(outT + nBNC);

    transpose2_kernel<<<dim3(N / 32, C / 32, B), dim3(32, 8), 0, stream>>>(
        x, xp, xT, xpT);
    colstats_kernel<<<(B * N + 255) / 256, 256, 0, stream>>>(x, cstat);
    ssim_main_kernel<<<(B * N) / 4, 256, 0, stream>>>(xT, xpT, cstat, e, outT);
    transpose_back_kernel<<<dim3(N / 32, C / 32, B), dim3(32, 8), 0, stream>>>(
        outT, out);
  } else {
    fallback_kernel<<<(B * N + 63) / 64, 64, 0, stream>>>(x, xp, e, out);
  }
}